// Round 7
// baseline (192.261 us; speedup 1.0000x reference)
//
#include <hip/hip_runtime.h>
#include <hip/hip_bf16.h>

// B=64, S=2048, D=256, VOCAB=288. M=131072, T derived host-side.
// KEY: out[i] depends only on code[i]=(day%7)*T+tod%T -> only 7T=2016 distinct
// output rows. Precompute Otab[2016][256] fp32 (2 MB, L2-resident), then
// main kernel = gather-copy (1KB coalesced load + store per row).
//   prep1: Htab[c] = relu(W1[c/T]+W1[7+c%T]+b1) bf16 ; W2S frag-linear ; TE probe
//   prep2: Otab = Htab(identity rows) @ W2 + b2   (R6-verified swapped MFMA)
//   copy : out[i] = Otab[code[i]]

typedef __bf16 bf16x4 __attribute__((ext_vector_type(4)));
typedef __bf16 bf16x8 __attribute__((ext_vector_type(8)));
typedef float  f32x4  __attribute__((ext_vector_type(4)));

#define M_TOTAL   131072

// ws: [0,131072) W2S ; [131072, +7T*512) Htab ; then Otab[2048][256] f32 ; then flag

// ---- prep1: Htab + W2S + TE dtype probe (verified R5/R6) -------------------
__global__ __launch_bounds__(64) void prep_all(const float* __restrict__ W1,
                                               const float* __restrict__ b1,
                                               const float* __restrict__ W2,
                                               __bf16* __restrict__ W2S,
                                               __bf16* __restrict__ Htab,
                                               const int* __restrict__ TE32,
                                               int* __restrict__ flag, int T) {
    const int b = blockIdx.x, lane = threadIdx.x;
    const int nTab = 7 * T;
    if (b < nTab) {
        const float* __restrict__ wa = W1 + (b / T) * 256;
        const float* __restrict__ wb = W1 + (7 + b % T) * 256;
        f32x4 a = *(const f32x4*)(wa + lane * 4);
        f32x4 c = *(const f32x4*)(wb + lane * 4);
        f32x4 d = *(const f32x4*)(b1 + lane * 4);
        bf16x4 h;
#pragma unroll
        for (int j = 0; j < 4; ++j) h[j] = (__bf16)fmaxf(a[j] + c[j] + d[j], 0.0f);
        *(bf16x4*)(Htab + b * 256 + lane * 4) = h;
    } else {
        const int wb = b - nTab;               // 0..63
        // W2S chunk c=(nt*8+ks)*64+l ; elem j -> W2[ks*32+(l>>4)*8+j][nt*16+(l&15)]
#pragma unroll
        for (int q = 0; q < 2; ++q) {
            int c = (wb * 64 + lane) * 2 + q;  // 0..8191
            int l = c & 63, ksnt = c >> 6;
            int ks = ksnt & 7, nt = ksnt >> 3;
            int n  = nt * 16 + (l & 15);
            int k0 = ks * 32 + (l >> 4) * 8;
            bf16x8 w;
#pragma unroll
            for (int j = 0; j < 8; ++j) w[j] = (__bf16)W2[(k0 + j) * 256 + n];
            *(bf16x8*)(W2S + c * 8) = w;
        }
        if (wb == 0) {  // int64 => odd int32 words all zero
            int v = 0;
            for (int i = lane; i < 2048; i += 64) v |= TE32[2 * i + 1];
            unsigned long long nz = __ballot(v != 0);
            if (lane == 0) *flag = (nz == 0ull) ? 1 : 0;
        }
    }
}

// ---- prep2: Otab[row] = Htab[row] @ W2 + b2 (rows 0..2047, clamped reads) --
// Operand-swapped MFMA exactly as R6 (verified): A-op = W2 frag, B-op = h frag.
__global__ __launch_bounds__(256) void otab_gemm(
        const __bf16* __restrict__ Htab, // [7T][256]
        const __bf16* __restrict__ W2S,  // fragment-linear
        const float* __restrict__ b2,
        float* __restrict__ Otab, int T) // [2048][256]
{
    const int wave = threadIdx.x >> 6;
    const int lane = threadIdx.x & 63;
    const int m    = lane & 15;
    const int quad = lane >> 4;
    const int rowBase = blockIdx.x * 128 + wave * 32;
    const int nTab = 7 * T;

    bf16x8 hfrag[2][8];
#pragma unroll
    for (int t = 0; t < 2; ++t) {
        int row = rowBase + t * 16 + m;
        if (row >= nTab) row = nTab - 1;       // clamp (rows 2016..2047 garbage)
#pragma unroll
        for (int ks = 0; ks < 8; ++ks)
            hfrag[t][ks] = *(const bf16x8*)(Htab + row * 256 + ks * 32 + quad * 8);
    }
#pragma unroll 4
    for (int nt = 0; nt < 16; ++nt) {
        f32x4 acc0 = {0.f, 0.f, 0.f, 0.f};
        f32x4 acc1 = {0.f, 0.f, 0.f, 0.f};
#pragma unroll
        for (int ks = 0; ks < 8; ++ks) {
            bf16x8 wfrag = *(const bf16x8*)(W2S + ((nt * 8 + ks) * 64 + lane) * 8);
            acc0 = __builtin_amdgcn_mfma_f32_16x16x32_bf16(wfrag, hfrag[0][ks], acc0, 0, 0, 0);
            acc1 = __builtin_amdgcn_mfma_f32_16x16x32_bf16(wfrag, hfrag[1][ks], acc1, 0, 0, 0);
        }
        const f32x4 bias = *(const f32x4*)(b2 + nt * 16 + quad * 4);
        f32x4 v0, v1;
#pragma unroll
        for (int r = 0; r < 4; ++r) { v0[r] = acc0[r] + bias[r]; v1[r] = acc1[r] + bias[r]; }
        float* p0 = Otab + (rowBase + m) * 256 + nt * 16 + quad * 4;
        *(f32x4*)p0 = v0;
        *(f32x4*)(p0 + 16 * 256) = v1;
    }
}

// ---- main: pure gather-copy out[i] = Otab[code[i]] -------------------------
__global__ __launch_bounds__(256, 8) void temb_copy(
        const int*   __restrict__ TE32,  // [M,2] int32/int64 word view
        const float* __restrict__ Otab,  // [2048][256] fp32, L2-resident
        const int*   __restrict__ flag,
        float* __restrict__ out, int T)
{
    const int is64 = *flag;              // wave-uniform
    const int wave = threadIdx.x >> 6;
    const int lane = threadIdx.x & 63;
    const int rowBase = blockIdx.x * 128 + wave * 32;

    int code = 0;
    if (lane < 32) {                     // codes for this wave's 32 rows
        const int row = rowBase + lane;
        int day, tod;
        if (is64) { int4 te = *(const int4*)(TE32 + 4 * row); day = te.x; tod = te.z; }
        else      { int2 te = *(const int2*)(TE32 + 2 * row); day = te.x; tod = te.y; }
        code = (day % 7) * T + (tod % T);
    }
    // 32 rows: each is one 1KB coalesced load (L2-hit) + one 1KB coalesced store
#pragma unroll 8
    for (int r = 0; r < 32; ++r) {
        const int c = __shfl(code, r);
        const f32x4 v = *(const f32x4*)(Otab + c * 256 + lane * 4);
        *(f32x4*)(out + (size_t)(rowBase + r) * 256 + lane * 4) = v;
    }
}

extern "C" void kernel_launch(void* const* d_in, const int* in_sizes, int n_in,
                              void* d_out, int out_size, void* d_ws, size_t ws_size,
                              hipStream_t stream) {
    const int*   TE = (const int*)  d_in[0];   // [B,S,2] integer words
    const float* W1 = (const float*)d_in[2];   // [7+T,256]
    const float* b1 = (const float*)d_in[3];   // [256]
    const float* W2 = (const float*)d_in[4];   // [256,256]
    const float* b2 = (const float*)d_in[5];   // [256]
    const int T = in_sizes[2] / 256 - 7;       // 288

    char* ws = (char*)d_ws;
    __bf16* W2S  = (__bf16*)ws;                                  // 128 KB
    __bf16* Htab = (__bf16*)(ws + 131072);                       // 7T*512 B
    float*  Otab = (float*) (ws + 131072 + (size_t)7 * T * 512); // 2048*1KB
    int*    flag = (int*)   (ws + 131072 + (size_t)7 * T * 512 + 2048 * 1024);
    float*  out  = (float*)d_out;

    prep_all<<<7 * T + 64, 64, 0, stream>>>(W1, b1, W2, W2S, Htab, TE, flag, T);
    otab_gemm<<<16, 256, 0, stream>>>(Htab, W2S, b2, Otab, T);
    temb_copy<<<M_TOTAL / 128, 256, 0, stream>>>(TE, Otab, flag, out, T);
}